// Round 2
// baseline (222.708 us; speedup 1.0000x reference)
//
#include <hip/hip_runtime.h>

#define NV   10
#define DD   2048
#define TAPS 25
#define CHUNK 128
#define OB   64

__device__ __forceinline__ float bsign(float v) {
    return (v > 0.0f) ? 1.0f : ((v < 0.0f) ? -1.0f : 0.0f);
}

// G[tap][n][o] = sum_c sign(values[n][c]) * sign(w[o][c][tap])
// one block per o; 250 active threads = (cg in 0..24) x (n in 0..9)
__global__ __launch_bounds__(256) void g_kernel(
        const float* __restrict__ values,
        const float* __restrict__ w,
        float* __restrict__ G) {
    const int o = blockIdx.x;
    const int t = threadIdx.x;

    __shared__ float ls_w[CHUNK][28];    // binarized w chunk [cc][tap], 25 padded to 28 (16B-aligned rows)
    __shared__ float g_loc[NV * TAPS];

    if (t < NV * TAPS) g_loc[t] = 0.0f;

    const int cg = t / NV;               // 0..24 for active threads
    const int n  = t - cg * NV;          // 0..9
    const bool active = (t < NV * TAPS); // t < 250

    float acc[TAPS];
    #pragma unroll
    for (int i = 0; i < TAPS; ++i) acc[i] = 0.0f;

    const float* wo   = w + (size_t)o * (DD * TAPS);
    const float* vrow = values + n * DD;

    for (int chunk = 0; chunk < DD / CHUNK; ++chunk) {
        const int c0 = chunk * CHUNK;
        __syncthreads();                 // protect ls_w overwrite vs previous reads
        // stage + binarize w[o][c0:c0+128][0:25]: 3200 contiguous floats = 800 float4
        const float4* src = (const float4*)(wo + (size_t)c0 * TAPS);
        for (int e = t; e < (CHUNK * TAPS) / 4; e += 256) {
            float4 v = src[e];
            int i0 = e * 4;
            int c_, p_;
            c_ = i0 / TAPS; p_ = i0 - c_ * TAPS;         ls_w[c_][p_] = bsign(v.x);
            i0++; c_ = i0 / TAPS; p_ = i0 - c_ * TAPS;   ls_w[c_][p_] = bsign(v.y);
            i0++; c_ = i0 / TAPS; p_ = i0 - c_ * TAPS;   ls_w[c_][p_] = bsign(v.z);
            i0++; c_ = i0 / TAPS; p_ = i0 - c_ * TAPS;   ls_w[c_][p_] = bsign(v.w);
        }
        __syncthreads();
        if (active) {
            #pragma unroll 1
            for (int cc = cg; cc < CHUNK; cc += TAPS) {  // 5-6 c's per thread per chunk
                const float sv = bsign(vrow[c0 + cc]);   // values: L1/L2-hot (80 KB total)
                #pragma unroll
                for (int tap = 0; tap < TAPS; ++tap)
                    acc[tap] += sv * ls_w[cc][tap];      // 10-lane same-address broadcast
            }
        }
    }
    // reduce the 25 cg-partials per (n,tap); all values are exact small integers in f32,
    // so atomic order does not affect the result (deterministic).
    if (active) {
        #pragma unroll
        for (int tap = 0; tap < TAPS; ++tap)
            atomicAdd(&g_loc[n * TAPS + tap], acc[tap]);
    }
    __syncthreads();
    if (t < NV * TAPS) {
        const int nn  = t / TAPS;
        const int tap = t - nn * TAPS;
        G[((size_t)(tap * NV + nn) << 11) + o] = g_loc[t];
    }
}

// out[b,o,oh,ow] = sign(sum_tap G[idx(tap)][o][tap] + bias[o])
// The tap-sum is an exact (even) integer in f32; bias is added ONCE at the end so that
// sign() matches the reference bit-exactly (including the conv_sum == 0 -> sign(bias) case).
__global__ __launch_bounds__(256) void out_kernel(
        const float* __restrict__ x,
        const float* __restrict__ G,
        const float* __restrict__ bias,
        float* __restrict__ out) {
    const int b     = blockIdx.x >> 5;
    const int oc    = blockIdx.x & 31;
    const int obase = oc * OB;
    const int t     = threadIdx.x;

    __shared__ int   s_idx[28 * 28];
    __shared__ float s_out[OB * 145];    // [o_l][pos], stride 145 (odd word-stride: conflict-free)

    for (int e = t; e < 28 * 28; e += 256) {
        s_idx[e] = (int)(x[b * 784 + e] * 9.0f);   // trunc, matches .astype(int32)
    }
    __syncthreads();

    const int o_l = t & (OB - 1);        // 0..63 (one full wave per pg)
    const int pg  = t >> 6;              // 0..3: 4 output positions per iteration
    const float bv = bias[obase + o_l];
    const float* Gb = G + obase + o_l;

    for (int p0 = 0; p0 < 144; p0 += 4) {
        const int pos = p0 + pg;
        const int oh  = pos / 12;
        const int ow  = pos - oh * 12;
        float acc = 0.0f;                              // integer-exact accumulation
        #pragma unroll
        for (int kh = 0; kh < 5; ++kh) {
            const int row = (oh * 2 + kh) * 28 + ow * 2;
            #pragma unroll
            for (int kw = 0; kw < 5; ++kw) {
                const int n   = s_idx[row + kw];           // wave-uniform broadcast
                const int tap = kh * 5 + kw;
                acc += Gb[(size_t)(tap * NV + n) << 11];   // coalesced 256B/wave, L2-hit
            }
        }
        s_out[o_l * 145 + pos] = bsign(acc + bv);      // bias added once, after exact int sum
    }
    __syncthreads();

    // block's output region is one contiguous span of OB*144 floats
    float* dst = out + ((size_t)(b * DD + obase)) * 144;
    for (int e = t; e < OB * 144; e += 256) {
        const int ol = e / 144;
        dst[e] = s_out[ol * 145 + (e - ol * 144)];
    }
}

extern "C" void kernel_launch(void* const* d_in, const int* in_sizes, int n_in,
                              void* d_out, int out_size, void* d_ws, size_t ws_size,
                              hipStream_t stream) {
    const float* x      = (const float*)d_in[0];   // [16,1,28,28]
    const float* values = (const float*)d_in[1];   // [10,2048]
    const float* w      = (const float*)d_in[2];   // [2048,2048,5,5] OIHW
    const float* bias   = (const float*)d_in[3];   // [2048]
    float* out = (float*)d_out;                    // [16,2048,12,12]
    float* G   = (float*)d_ws;                     // 25*10*2048 floats = 2 MB scratch

    hipLaunchKernelGGL(g_kernel, dim3(DD), dim3(256), 0, stream, values, w, G);
    hipLaunchKernelGGL(out_kernel, dim3(16 * (DD / OB)), dim3(256), 0, stream, x, G, bias, out);
}

// Round 3
// 137.292 us; speedup vs baseline: 1.6221x; 1.6221x over previous
//
#include <hip/hip_runtime.h>

#define NV   10
#define DD   2048
#define TAPS 25
#define CHUNK 128             // channels per staging chunk
#define NCH  (DD / CHUNK)     // 16 chunks
#define NGRP (DD / 64)        // 32 groups of 64 channels
#define OB   64

typedef __attribute__((address_space(1))) const unsigned int gu32;
typedef __attribute__((address_space(3))) unsigned int lu32;

__device__ __forceinline__ float bsign(float v) {
    return (v > 0.0f) ? 1.0f : ((v < 0.0f) ? -1.0f : 0.0f);
}

// Pack sign/nonzero bitmasks of values: one block per (n, 64-ch group).
__global__ __launch_bounds__(64) void vpack_kernel(
        const float* __restrict__ values,
        unsigned long long* __restrict__ vnz,
        unsigned long long* __restrict__ vng) {
    const int b    = blockIdx.x;      // 0..319
    const int n    = b >> 5;
    const int g    = b & 31;
    const int lane = threadIdx.x;
    float f = values[n * DD + g * 64 + lane];
    unsigned long long nz = __ballot(f != 0.0f);
    unsigned long long ng = __ballot(f < 0.0f);
    if (lane == 0) {
        vnz[n * NGRP + g] = nz;
        vng[n * NGRP + g] = ng;
    }
}

// G[tap][n][o] = sum_c sign(values[n][c])*sign(w[o][c][tap]), via xor+popcount.
// One block per o. Stage raw w to LDS (global_load_lds, linear), ballot-pack,
// popcount-accumulate. All values exact small ints in f32 -> bit-exact.
__global__ __launch_bounds__(256) void g_kernel(
        const float* __restrict__ w,
        const unsigned long long* __restrict__ gvnz,
        const unsigned long long* __restrict__ gvng,
        float* __restrict__ G) {
    const int o    = blockIdx.x;
    const int t    = threadIdx.x;
    const int lane = t & 63;
    const int wv   = t >> 6;

    __shared__ float ls_raw[CHUNK * TAPS + 32];      // 3200 floats, linear
    __shared__ unsigned long long s_wnz[TAPS * 2];
    __shared__ unsigned long long s_wng[TAPS * 2];
    __shared__ unsigned long long s_vnz[NV * NGRP];
    __shared__ unsigned long long s_vng[NV * NGRP];

    for (int e = t; e < NV * NGRP; e += 256) {
        s_vnz[e] = gvnz[e];
        s_vng[e] = gvng[e];
    }

    const int tap = t / NV;          // accum ownership: t<250 -> (tap, n)
    const int n   = t - tap * NV;
    int acc = 0;

    const float* wo = w + (size_t)o * (DD * TAPS);

    for (int ch = 0; ch < NCH; ++ch) {
        __syncthreads();  // prev pack done reading ls_raw; prev accum done reading masks
        // stage 3200 floats = 800 float4 direct to LDS (linear, wave-uniform base + lane*16)
        const float* src = wo + (size_t)(ch * CHUNK) * TAPS;
        for (int e = t; e < (CHUNK * TAPS) / 4; e += 256) {
            const float* gp = src + 4 * e;
            float* lp = ls_raw + 4 * (e - lane);     // uniform within wave
            __builtin_amdgcn_global_load_lds((gu32*)gp, (lu32*)lp, 16, 0, 0);
        }
        __syncthreads();  // drains vmcnt -> ls_raw valid
        // pack: 50 tasks = (tap, 64c-subgroup); stride-25-word LDS reads (2/bank, free)
        for (int task = wv; task < TAPS * 2; task += 4) {
            const int ptap = task >> 1;
            const int sub  = task & 1;
            float f = ls_raw[(sub * 64 + lane) * TAPS + ptap];
            unsigned long long nz = __ballot(f != 0.0f);
            unsigned long long ng = __ballot(f < 0.0f);
            if (lane == 0) { s_wnz[task] = nz; s_wng[task] = ng; }
        }
        __syncthreads();
        // accumulate: S += popc(bothnz) - 2*popc(signdiff & bothnz)  (exact, incl. zeros)
        if (t < NV * TAPS) {
            #pragma unroll
            for (int sub = 0; sub < 2; ++sub) {
                unsigned long long wnz = s_wnz[tap * 2 + sub];
                unsigned long long wng = s_wng[tap * 2 + sub];
                unsigned long long vz  = s_vnz[n * NGRP + ch * 2 + sub];
                unsigned long long vg  = s_vng[n * NGRP + ch * 2 + sub];
                unsigned long long nzb = wnz & vz;
                unsigned long long df  = (wng ^ vg) & nzb;
                acc += __popcll(nzb) - 2 * __popcll(df);
            }
        }
    }
    if (t < NV * TAPS) {
        G[((size_t)(tap * NV + n) << 11) + o] = (float)acc;
    }
}

// out[b,o,oh,ow] = sign(sum_tap G[idx(tap)][o][tap] + bias[o])
// tap-sum is an exact integer in f32; bias added ONCE at the end (bit-exact sign).
__global__ __launch_bounds__(256) void out_kernel(
        const float* __restrict__ x,
        const float* __restrict__ G,
        const float* __restrict__ bias,
        float* __restrict__ out) {
    const int b     = blockIdx.x >> 5;
    const int oc    = blockIdx.x & 31;
    const int obase = oc * OB;
    const int t     = threadIdx.x;

    __shared__ int   s_idx[28 * 28];
    __shared__ float s_out[OB * 145];

    for (int e = t; e < 28 * 28; e += 256) {
        s_idx[e] = (int)(x[b * 784 + e] * 9.0f);   // trunc, matches .astype(int32)
    }
    __syncthreads();

    const int o_l = t & (OB - 1);
    const int pg  = t >> 6;
    const float bv = bias[obase + o_l];
    const float* Gb = G + obase + o_l;

    for (int p0 = 0; p0 < 144; p0 += 4) {
        const int pos = p0 + pg;
        const int oh  = pos / 12;
        const int ow  = pos - oh * 12;
        float acc = 0.0f;                              // integer-exact accumulation
        #pragma unroll
        for (int kh = 0; kh < 5; ++kh) {
            const int row = (oh * 2 + kh) * 28 + ow * 2;
            #pragma unroll
            for (int kw = 0; kw < 5; ++kw) {
                const int nn  = s_idx[row + kw];           // wave-uniform broadcast
                const int tp  = kh * 5 + kw;
                acc += Gb[(size_t)(tp * NV + nn) << 11];   // coalesced, L2-hit
            }
        }
        s_out[o_l * 145 + pos] = bsign(acc + bv);
    }
    __syncthreads();

    float* dst = out + ((size_t)(b * DD + obase)) * 144;
    for (int e = t; e < OB * 144; e += 256) {
        const int ol = e / 144;
        dst[e] = s_out[ol * 145 + (e - ol * 144)];
    }
}

extern "C" void kernel_launch(void* const* d_in, const int* in_sizes, int n_in,
                              void* d_out, int out_size, void* d_ws, size_t ws_size,
                              hipStream_t stream) {
    const float* x      = (const float*)d_in[0];   // [16,1,28,28]
    const float* values = (const float*)d_in[1];   // [10,2048]
    const float* w      = (const float*)d_in[2];   // [2048,2048,5,5] OIHW
    const float* bias   = (const float*)d_in[3];   // [2048]
    float* out = (float*)d_out;                    // [16,2048,12,12]

    unsigned long long* vnz = (unsigned long long*)d_ws;          // 2560 B
    unsigned long long* vng = vnz + NV * NGRP;                    // 2560 B
    float* G = (float*)((char*)d_ws + 8192);                      // 2 MB

    hipLaunchKernelGGL(vpack_kernel, dim3(NV * NGRP), dim3(64), 0, stream, values, vnz, vng);
    hipLaunchKernelGGL(g_kernel, dim3(DD), dim3(256), 0, stream, w, vnz, vng, G);
    hipLaunchKernelGGL(out_kernel, dim3(16 * (DD / OB)), dim3(256), 0, stream, x, G, bias, out);
}